// Round 1
// baseline (319.723 us; speedup 1.0000x reference)
//
#include <hip/hip_runtime.h>

#define NTOK 49
#define CH   128
#define NHEAD 4
#define SCALE 0.17677669529663687f   // 32^-0.5

typedef __bf16 bf16x8 __attribute__((ext_vector_type(8)));
typedef short  s16x8  __attribute__((ext_vector_type(8)));
typedef float  f32x4  __attribute__((ext_vector_type(4)));

__device__ __forceinline__ unsigned short f2bf(float f) {
  unsigned int u = __builtin_bit_cast(unsigned int, f);
  u += 0x7FFFu + ((u >> 16) & 1u);          // RNE
  return (unsigned short)(u >> 16);
}

__device__ __forceinline__ f32x4 mfma_bf16(s16x8 a, s16x8 b, f32x4 c) {
  return __builtin_amdgcn_mfma_f32_16x16x32_bf16(
      __builtin_bit_cast(bf16x8, a), __builtin_bit_cast(bf16x8, b), c, 0, 0, 0);
}

// ---------------- prep: weights -> bf16 transposed, rpb expand ----------------
// ws layout: wT bf16[384][128] @0 ; pT bf16[128][128] @98304B ; rpb f32[4][49*49] @131072B
__global__ void prep_kernel(const float* __restrict__ qkv_w,
                            const float* __restrict__ proj_w,
                            const float* __restrict__ bias_table,
                            unsigned short* __restrict__ wT,
                            unsigned short* __restrict__ pT,
                            float* __restrict__ rpb) {
  int t = blockIdx.x * 256 + threadIdx.x;
  if (t < 384 * 128) {
    int n = t >> 7, k = t & 127;
    float v = qkv_w[k * 384 + n];
    if (n < 128) v *= SCALE;                 // fold q scale into Wq
    wT[n * 128 + k] = f2bf(v);
  } else if (t < 384 * 128 + 128 * 128) {
    int u = t - 384 * 128;
    int n = u >> 7, k = u & 127;
    pT[n * 128 + k] = f2bf(proj_w[k * 128 + n]);
  } else if (t < 384 * 128 + 128 * 128 + NHEAD * NTOK * NTOK) {
    int u = t - (384 * 128 + 128 * 128);
    int h = u / (NTOK * NTOK);
    int ij = u % (NTOK * NTOK);
    int i = ij / NTOK, j = ij % NTOK;
    int idx = (i / 7 - j / 7 + 6) * 13 + (i % 7 - j % 7 + 6);
    rpb[h * (NTOK * NTOK) + ij] = bias_table[idx * NHEAD + h];
  }
}

// ---------------- fused: qkv + attention + proj, 1 window/WG, 1 head/wave ----------------
// LDS (76800 B): Xs bf16[64][136] (x tile, later AO)   @0      (17408 B)
//                per-wave q[64][40]+k[64][40], P[64][72] alias @17408  (40960 B)
//                per-wave vT[32][72]                           @58368  (18432 B)
__global__ __launch_bounds__(256, 2)
void attn_fused_kernel(const float* __restrict__ x,
                       const float* __restrict__ qkv_b,
                       const float* __restrict__ proj_b,
                       const float* __restrict__ mask,
                       const unsigned short* __restrict__ wT,
                       const unsigned short* __restrict__ pT,
                       const float* __restrict__ rpb,
                       float* __restrict__ out) {
  __shared__ __align__(16) char smem_raw[76800];
  unsigned short* const Xs     = (unsigned short*)smem_raw;           // [64][136]
  unsigned short* const QKbase = (unsigned short*)(smem_raw + 17408);
  unsigned short* const VTbase = (unsigned short*)(smem_raw + 58368);

  const int w    = blockIdx.x;
  const int tid  = threadIdx.x;
  const int wave = tid >> 6;        // == head
  const int lane = tid & 63;
  const int quad = lane >> 4;
  const int l16  = lane & 15;
  const int h    = wave;

  unsigned short* const qs = QKbase + wave * 5120;   // q [64][40]
  unsigned short* const ks = qs + 2560;              // k [64][40]
  unsigned short* const ps = QKbase + wave * 5120;   // P [64][72] (aliases q+k, used after)
  unsigned short* const vt = VTbase + wave * 2304;   // vT [32][72]

  const f32x4 fzero = {0.f, 0.f, 0.f, 0.f};

  // ---- stage x[w] fp32 -> bf16 LDS (zero-pad rows 49..63) ----
  {
    const float* xw = x + (size_t)w * (NTOK * CH);
    for (int t = tid; t < NTOK * 32; t += 256) {
      const int row = t >> 5;
      const int c4  = (t & 31) << 2;
      const float4 v = *(const float4*)(xw + row * CH + c4);
      ushort4 pk;
      pk.x = f2bf(v.x); pk.y = f2bf(v.y); pk.z = f2bf(v.z); pk.w = f2bf(v.w);
      *(ushort4*)(Xs + row * 136 + c4) = pk;
    }
    for (int t = tid; t < 15 * 32; t += 256) {
      const int row = 49 + (t >> 5);
      const int c4  = (t & 31) << 2;
      ushort4 z; z.x = 0; z.y = 0; z.z = 0; z.w = 0;
      *(ushort4*)(Xs + row * 136 + c4) = z;
    }
  }
  __syncthreads();

  // ---- QKV GEMM: wave h computes its head's q,k,v [64 x 32], K=128 ----
#pragma unroll
  for (int part = 0; part < 3; ++part) {     // 0=q 1=k 2=v
    f32x4 acc[4][2];
#pragma unroll
    for (int mt = 0; mt < 4; ++mt)
#pragma unroll
      for (int nt = 0; nt < 2; ++nt) acc[mt][nt] = fzero;
    const int nbase = part * 128 + h * 32;
#pragma unroll
    for (int kt = 0; kt < 4; ++kt) {
      s16x8 a[4], b[2];
#pragma unroll
      for (int mt = 0; mt < 4; ++mt)
        a[mt] = *(const s16x8*)(Xs + (mt * 16 + l16) * 136 + kt * 32 + quad * 8);
#pragma unroll
      for (int nt = 0; nt < 2; ++nt)
        b[nt] = *(const s16x8*)(wT + (size_t)(nbase + nt * 16 + l16) * 128 + kt * 32 + quad * 8);
#pragma unroll
      for (int mt = 0; mt < 4; ++mt)
#pragma unroll
        for (int nt = 0; nt < 2; ++nt)
          acc[mt][nt] = mfma_bf16(a[mt], b[nt], acc[mt][nt]);
    }
#pragma unroll
    for (int nt = 0; nt < 2; ++nt) {
      float bias = qkv_b[nbase + nt * 16 + l16];
      if (part == 0) bias *= SCALE;          // Wq pre-scaled; scale bias to match
#pragma unroll
      for (int mt = 0; mt < 4; ++mt)
#pragma unroll
        for (int r = 0; r < 4; ++r) {
          const int row = mt * 16 + quad * 4 + r;   // token
          const int col = nt * 16 + l16;            // d
          const unsigned short bv = f2bf(acc[mt][nt][r] + bias);
          if (part == 0)      qs[row * 40 + col] = bv;
          else if (part == 1) ks[row * 40 + col] = bv;
          else                vt[col * 72 + row] = bv;   // v transposed
        }
    }
  }
  __syncthreads();   // all waves done reading Xs (AO will alias it)

  // ---- S = q k^T  (16x16x32, K=d=32 in one MFMA) ----
  s16x8 qf[4], kf[4];
#pragma unroll
  for (int mt = 0; mt < 4; ++mt)
    qf[mt] = *(const s16x8*)(qs + (mt * 16 + l16) * 40 + quad * 8);
#pragma unroll
  for (int nt = 0; nt < 4; ++nt)
    kf[nt] = *(const s16x8*)(ks + (nt * 16 + l16) * 40 + quad * 8);
  f32x4 s[4][4];
#pragma unroll
  for (int mt = 0; mt < 4; ++mt)
#pragma unroll
    for (int nt = 0; nt < 4; ++nt)
      s[mt][nt] = mfma_bf16(qf[mt], kf[nt], fzero);

  // ---- logits = S + rpb[h] + mask[w%64]; row softmax; P (unnormalized) -> LDS bf16 ----
  const float* maskw = mask + (size_t)(w & 63) * (NTOK * NTOK);
  const float* rpbh  = rpb + h * (NTOK * NTOK);
  float rinv[4][4];
#pragma unroll
  for (int mt = 0; mt < 4; ++mt) {
#pragma unroll
    for (int r = 0; r < 4; ++r) {
      const int i = mt * 16 + quad * 4 + r;
      float vals[4];
      float vmax = -1e30f;
#pragma unroll
      for (int nt = 0; nt < 4; ++nt) {
        const int j = nt * 16 + l16;
        float v = -1e30f;                       // pad cols -> P=0
        if (i < NTOK && j < NTOK) {
          const int ij = i * NTOK + j;
          v = s[mt][nt][r] + rpbh[ij] + maskw[ij];
        }
        vals[nt] = v;
        vmax = fmaxf(vmax, v);
      }
#pragma unroll
      for (int off = 1; off < 16; off <<= 1)    // row spans 16 lanes of this quad-group
        vmax = fmaxf(vmax, __shfl_xor(vmax, off, 64));
      float rsum = 0.f;
#pragma unroll
      for (int nt = 0; nt < 4; ++nt) {
        const float e = __expf(vals[nt] - vmax);
        vals[nt] = e;
        rsum += e;
      }
#pragma unroll
      for (int off = 1; off < 16; off <<= 1)
        rsum += __shfl_xor(rsum, off, 64);
      rinv[mt][r] = 1.f / rsum;                 // normalization deferred to after PV
#pragma unroll
      for (int nt = 0; nt < 4; ++nt)
        ps[i * 72 + nt * 16 + l16] = f2bf(vals[nt]);
    }
  }

  // ---- O = P v  (M=64, N=32, K=64) ----
  f32x4 o[4][2];
#pragma unroll
  for (int mt = 0; mt < 4; ++mt)
#pragma unroll
    for (int nt = 0; nt < 2; ++nt) o[mt][nt] = fzero;
#pragma unroll
  for (int kt = 0; kt < 2; ++kt) {
    s16x8 pf[4], vf[2];
#pragma unroll
    for (int mt = 0; mt < 4; ++mt)
      pf[mt] = *(const s16x8*)(ps + (mt * 16 + l16) * 72 + kt * 32 + quad * 8);
#pragma unroll
    for (int nt = 0; nt < 2; ++nt)
      vf[nt] = *(const s16x8*)(vt + (nt * 16 + l16) * 72 + kt * 32 + quad * 8);
#pragma unroll
    for (int mt = 0; mt < 4; ++mt)
#pragma unroll
      for (int nt = 0; nt < 2; ++nt)
        o[mt][nt] = mfma_bf16(pf[mt], vf[nt], o[mt][nt]);
  }

  // ---- AO (normalized, bf16) -> LDS [64][136] (token, h*32+d), aliases Xs ----
  unsigned short* const ao = Xs;
#pragma unroll
  for (int mt = 0; mt < 4; ++mt)
#pragma unroll
    for (int nt = 0; nt < 2; ++nt)
#pragma unroll
      for (int r = 0; r < 4; ++r) {
        const int row = mt * 16 + quad * 4 + r;
        const int col = h * 32 + nt * 16 + l16;
        ao[row * 136 + col] = f2bf(o[mt][nt][r] * rinv[mt][r]);
      }
  __syncthreads();

  // ---- proj: out[64 x 128] = AO @ proj_w + b; wave h does cols [h*32, h*32+32) ----
  f32x4 po[4][2];
#pragma unroll
  for (int mt = 0; mt < 4; ++mt)
#pragma unroll
    for (int nt = 0; nt < 2; ++nt) po[mt][nt] = fzero;
#pragma unroll
  for (int kt = 0; kt < 4; ++kt) {
    s16x8 a[4], b[2];
#pragma unroll
    for (int mt = 0; mt < 4; ++mt)
      a[mt] = *(const s16x8*)(ao + (mt * 16 + l16) * 136 + kt * 32 + quad * 8);
#pragma unroll
    for (int nt = 0; nt < 2; ++nt)
      b[nt] = *(const s16x8*)(pT + (size_t)(h * 32 + nt * 16 + l16) * 128 + kt * 32 + quad * 8);
#pragma unroll
    for (int mt = 0; mt < 4; ++mt)
#pragma unroll
      for (int nt = 0; nt < 2; ++nt)
        po[mt][nt] = mfma_bf16(a[mt], b[nt], po[mt][nt]);
  }
  float* outw = out + (size_t)w * (NTOK * CH);
#pragma unroll
  for (int nt = 0; nt < 2; ++nt) {
    const int col = h * 32 + nt * 16 + l16;
    const float pb = proj_b[col];
#pragma unroll
    for (int mt = 0; mt < 4; ++mt)
#pragma unroll
      for (int r = 0; r < 4; ++r) {
        const int row = mt * 16 + quad * 4 + r;
        if (row < NTOK) outw[row * CH + col] = po[mt][nt][r] + pb;
      }
  }
}

extern "C" void kernel_launch(void* const* d_in, const int* in_sizes, int n_in,
                              void* d_out, int out_size, void* d_ws, size_t ws_size,
                              hipStream_t stream) {
  (void)in_sizes; (void)n_in; (void)out_size; (void)ws_size;
  const float* x          = (const float*)d_in[0];
  const float* qkv_w      = (const float*)d_in[1];
  const float* qkv_b      = (const float*)d_in[2];
  const float* proj_w     = (const float*)d_in[3];
  const float* proj_b     = (const float*)d_in[4];
  const float* bias_table = (const float*)d_in[5];
  const float* mask       = (const float*)d_in[6];
  float* out = (float*)d_out;

  unsigned short* wT = (unsigned short*)d_ws;          // 384*128 bf16
  unsigned short* pT = wT + 384 * 128;                 // 128*128 bf16
  float* rpb = (float*)(pT + 128 * 128);               // 4*49*49 f32 (@131072 B)

  const int prep_items = 384 * 128 + 128 * 128 + NHEAD * NTOK * NTOK;
  prep_kernel<<<(prep_items + 255) / 256, 256, 0, stream>>>(qkv_w, proj_w, bias_table,
                                                            wT, pT, rpb);
  attn_fused_kernel<<<4096, 256, 0, stream>>>(x, qkv_b, proj_b, mask, wT, pT, rpb, out);
}